// Round 20
// baseline (321.371 us; speedup 1.0000x reference)
//
#include <hip/hip_runtime.h>
#include <math.h>

#define B_   8
#define T_   256
#define U_   64
#define UP1  65
#define DE   640
#define J_   512
#define V_   1024
#define NCELL (B_ * T_ * UP1)
#define LOG0 -1e30f
#define NSEG 8
#define SEGLEN 32
#define MLD  66   // matrix column leading dim (65 rows + 1 pad)

typedef __attribute__((ext_vector_type(4))) float f32x4;
typedef __attribute__((ext_vector_type(8))) short short8;

__device__ __forceinline__ unsigned short f2bf(float x) {
    union { float f; unsigned int u; } c; c.f = x;
    unsigned int r = (c.u + 0x7fffu + ((c.u >> 16) & 1u)) >> 16;  // RNE
    return (unsigned short)r;
}

// ---------------- DPP wave64 scan/reduce helpers -------------------------------------
template<int CTRL, int RM>
__device__ __forceinline__ float dppz(float x) {
    return __builtin_bit_cast(float,
        __builtin_amdgcn_update_dpp(0, __builtin_bit_cast(int, x), CTRL, RM, 0xf, false));
}
template<int CTRL, int RM>
__device__ __forceinline__ float dpps(float x) {
    int xi = __builtin_bit_cast(int, x);
    return __builtin_bit_cast(float,
        __builtin_amdgcn_update_dpp(xi, xi, CTRL, RM, 0xf, false));
}
__device__ __forceinline__ float wave_prefix_sum(float v) {
    v += dppz<0x111, 0xf>(v);
    v += dppz<0x112, 0xf>(v);
    v += dppz<0x114, 0xf>(v);
    v += dppz<0x118, 0xf>(v);
    v += dppz<0x142, 0xa>(v);
    v += dppz<0x143, 0xc>(v);
    return v;
}
__device__ __forceinline__ float wave_max_all(float v) {
    v = fmaxf(v, dpps<0x111, 0xf>(v));
    v = fmaxf(v, dpps<0x112, 0xf>(v));
    v = fmaxf(v, dpps<0x114, 0xf>(v));
    v = fmaxf(v, dpps<0x118, 0xf>(v));
    v = fmaxf(v, dpps<0x142, 0xa>(v));
    v = fmaxf(v, dpps<0x143, 0xc>(v));
    return __builtin_bit_cast(float,
        __builtin_amdgcn_readlane(__builtin_bit_cast(int, v), 63));
}
__device__ __forceinline__ float rdlane(float v, int l) {
    return __builtin_bit_cast(float,
        __builtin_amdgcn_readlane(__builtin_bit_cast(int, v), l));
}

// ---- Kernel P: prep (weights + inputs + W_out fp8). Block ranges:
// [0,160) wf2e, [160,320) wf2p, [320,960) enc->bf16, [960,1123) pred->bf16,
// [1123,1635) W_out -> fp8 frag-major Wf (old wt_kernel).
__global__ __launch_bounds__(256) void prep_kernel(const float* __restrict__ We,
                                                   const float* __restrict__ Wp,
                                                   const float* __restrict__ enc,
                                                   const float* __restrict__ pred,
                                                   const float* __restrict__ Wout,
                                                   unsigned short* __restrict__ wf2e,
                                                   unsigned short* __restrict__ wf2p,
                                                   unsigned short* __restrict__ encB,
                                                   unsigned short* __restrict__ predB,
                                                   unsigned char* __restrict__ Wf) {
    int bx = blockIdx.x, tid = threadIdx.x;
    if (bx < 320) {
        const float* W = (bx < 160) ? We : Wp;
        unsigned short* dst = (bx < 160) ? wf2e : wf2p;
        int gid = ((bx < 160) ? bx : bx - 160) * 256 + tid;
        int lane = gid & 63, ktl = gid >> 6;
        int kt = ktl % 20, tl = ktl / 20;
        int lg = lane >> 4, ln = lane & 15;
        int col = tl * 16 + ln;
        short8 v;
#pragma unroll
        for (int j = 0; j < 8; ++j)
            v[j] = (short)f2bf(W[(size_t)(kt * 32 + lg * 8 + j) * J_ + col]);
        *(short8*)(dst + (size_t)gid * 8) = v;
    } else if (bx < 960) {
        int gid = (bx - 320) * 256 + tid;
        const float* s = enc + (size_t)gid * 8;
        float4 a = *(const float4*)s, b = *(const float4*)(s + 4);
        short8 v;
        v[0] = (short)f2bf(a.x); v[1] = (short)f2bf(a.y);
        v[2] = (short)f2bf(a.z); v[3] = (short)f2bf(a.w);
        v[4] = (short)f2bf(b.x); v[5] = (short)f2bf(b.y);
        v[6] = (short)f2bf(b.z); v[7] = (short)f2bf(b.w);
        *(short8*)(encB + (size_t)gid * 8) = v;
    } else if (bx < 1123) {
        int gid = (bx - 960) * 256 + tid;
        if (gid < 41600) {
            const float* s = pred + (size_t)gid * 8;
            float4 a = *(const float4*)s, b = *(const float4*)(s + 4);
            short8 v;
            v[0] = (short)f2bf(a.x); v[1] = (short)f2bf(a.y);
            v[2] = (short)f2bf(a.z); v[3] = (short)f2bf(a.w);
            v[4] = (short)f2bf(b.x); v[5] = (short)f2bf(b.y);
            v[6] = (short)f2bf(b.z); v[7] = (short)f2bf(b.w);
            *(short8*)(predB + (size_t)gid * 8) = v;
        }
    } else {
        // W_out[512][1024] -> fp8 frag-major (round-6 K32 layout)
        __shared__ float tile[32][33];
        int bx2 = bx - 1123;                 // 0..511
        int tx = tid & 31, ty = tid >> 5;
        int v0 = (bx2 & 31) * 32, k0 = (bx2 >> 5) * 32;
#pragma unroll
        for (int i = 0; i < 4; ++i)
            tile[ty + i * 8][tx] = Wout[(size_t)(k0 + ty + i * 8) * V_ + v0 + tx];
        __syncthreads();
        if (tid < 128) {
            int vl = tid >> 2, lg = tid & 3;
            int v  = v0 + vl;
            float x[8];
#pragma unroll
            for (int j = 0; j < 8; ++j) x[j] = tile[lg * 8 + j][vl];
            int lo = 0, hi = 0;
            lo = __builtin_amdgcn_cvt_pk_fp8_f32(x[0], x[1], lo, false);
            lo = __builtin_amdgcn_cvt_pk_fp8_f32(x[2], x[3], lo, true);
            hi = __builtin_amdgcn_cvt_pk_fp8_f32(x[4], x[5], hi, false);
            hi = __builtin_amdgcn_cvt_pk_fp8_f32(x[6], x[7], hi, true);
            int tl = v >> 4, ln = v & 15, kt = k0 >> 5;
            *(int2*)(Wf + tl * 8192 + kt * 512 + (lg * 16 + ln) * 8) = make_int2(lo, hi);
        }
    }
}

// ---- Kernel A: bf16 MFMA input GEMM (enc & pred in one dispatch). 1 wave = 64x64. ----
__global__ __launch_bounds__(64) void gemm_mfma(const unsigned short* __restrict__ encB,
                                                const unsigned short* __restrict__ predB,
                                                const unsigned short* __restrict__ wf2e,
                                                const unsigned short* __restrict__ wf2p,
                                                const float* __restrict__ bj,
                                                float* __restrict__ ep,
                                                float* __restrict__ pp) {
    int rt = blockIdx.x, ct = blockIdx.y;
    int lane = threadIdx.x;
    const unsigned short* A;
    const short8* wp;
    float* C;
    const float* bias;
    int M, row0;
    if (rt < 32) { A = encB;  wp = (const short8*)wf2e; C = ep; bias = bj;      M = 2048; row0 = rt * 64; }
    else         { A = predB; wp = (const short8*)wf2p; C = pp; bias = nullptr; M = 520;  row0 = (rt - 32) * 64; }
    int lg = lane >> 4, ln = lane & 15;

    int r_[4];
#pragma unroll
    for (int mi = 0; mi < 4; ++mi) {
        int rr = row0 + mi * 16 + ln;
        r_[mi] = (rr < M) ? rr : (M - 1);
    }

#define WIDX(NI, KT) (((size_t)((ct * 4 + (NI)) * 20 + (KT))) * 64 + lane)
    short8 bf[3][4], af[2][4];
#pragma unroll
    for (int ni = 0; ni < 4; ++ni) bf[0][ni] = wp[WIDX(ni, 0)];
#pragma unroll
    for (int ni = 0; ni < 4; ++ni) bf[1][ni] = wp[WIDX(ni, 1)];
#pragma unroll
    for (int mi = 0; mi < 4; ++mi)
        af[0][mi] = *(const short8*)(A + (size_t)r_[mi] * DE + lg * 8);

    f32x4 acc[4][4] = {};
#pragma unroll
    for (int kt = 0; kt < 20; ++kt) {
        const int cur3 = kt % 3;
        const int pf3  = (kt + 2) % 3;
        const int cur  = kt & 1, nxt = cur ^ 1;
#pragma unroll
        for (int ni = 0; ni < 4; ++ni) {
            if (kt < 18) bf[pf3][ni] = wp[WIDX(ni, kt + 2)];
            __builtin_amdgcn_s_setprio(1);
#pragma unroll
            for (int mi = 0; mi < 4; ++mi)
                acc[mi][ni] = __builtin_amdgcn_mfma_f32_16x16x32_bf16(
                    af[cur][mi], bf[cur3][ni], acc[mi][ni], 0, 0, 0);
            __builtin_amdgcn_s_setprio(0);
            if (ni == 1 && kt < 19) {
#pragma unroll
                for (int mi = 0; mi < 4; ++mi)
                    af[nxt][mi] = *(const short8*)(A + (size_t)r_[mi] * DE +
                                                   (kt + 1) * 32 + lg * 8);
            }
        }
    }
#undef WIDX

#pragma unroll
    for (int mi = 0; mi < 4; ++mi) {
#pragma unroll
        for (int r = 0; r < 4; ++r) {
            int row = row0 + mi * 16 + lg * 4 + r;
            if (row >= M) continue;
#pragma unroll
            for (int ni = 0; ni < 4; ++ni) {
                int col = ct * 64 + ni * 16 + ln;
                float v = acc[mi][ni][r];
                if (bias) v += bias[col];
                C[(size_t)row * J_ + col] = v;
            }
        }
    }
}

// ---- Kernel H: h = tanh(ep+pp) fp8, FRAGMENT-MAJOR per 64-cell tile ------------------
// 8B unit q (0..4095): lane=q&63 (ln=lane&15, lg=lane>>4), ktmi=q>>6 (kt=ktmi&15,
// mi=ktmi>>4). Unit holds h[mi*16+ln][kt*32+lg*8 .. +8]. Joint A-frag (mi,kt) is then
// one contiguous 512B wave read: hf[(mi<<10)+(kt<<6)+lane].
__global__ __launch_bounds__(512) void hgen_kernel(const float* __restrict__ ep,
                                                   const float* __restrict__ pp,
                                                   unsigned char* __restrict__ hG) {
    int tid  = threadIdx.x;
    int tile = blockIdx.x;
    long* outb = (long*)(hG + (size_t)tile * 32768);
#pragma unroll
    for (int i = 0; i < 8; ++i) {
        int q    = tid + i * 512;
        int lane = q & 63;
        int ktmi = q >> 6;
        int kt = ktmi & 15, mi = ktmi >> 4;
        int ln = lane & 15, lg = lane >> 4;
        int row = mi * 16 + ln;
        int k   = kt * 32 + lg * 8;
        int cell = tile * 64 + row;
        unsigned epRow = (unsigned)cell / 65u;
        int u = cell - (int)epRow * 65;
        int b = (int)(epRow >> 8);
        const float* epr = ep + (size_t)epRow * J_ + k;
        const float* ppr = pp + (size_t)(b * UP1 + u) * J_ + k;
        float4 e0 = *(const float4*)epr, e1 = *(const float4*)(epr + 4);
        float4 p0 = *(const float4*)ppr, p1 = *(const float4*)(ppr + 4);
        float x[8] = {e0.x + p0.x, e0.y + p0.y, e0.z + p0.z, e0.w + p0.w,
                      e1.x + p1.x, e1.y + p1.y, e1.z + p1.z, e1.w + p1.w};
        float t[8];
#pragma unroll
        for (int j = 0; j < 8; ++j) {
            float e2 = __expf(2.f * x[j]);
            t[j] = 1.f - 2.f / (e2 + 1.f);
        }
        int lo = 0, hi = 0;
        lo = __builtin_amdgcn_cvt_pk_fp8_f32(t[0], t[1], lo, false);
        lo = __builtin_amdgcn_cvt_pk_fp8_f32(t[2], t[3], lo, true);
        hi = __builtin_amdgcn_cvt_pk_fp8_f32(t[4], t[5], hi, false);
        hi = __builtin_amdgcn_cvt_pk_fp8_f32(t[6], t[7], hi, true);
        outb[q] = ((long)(unsigned)hi << 32) | (unsigned)lo;
    }
}

// ---- Kernel B: fp8-K32 joint, NO LDS STAGING (A-frags direct from L2 frag-major hF) --
// bx -> tile=(bx>>5)*8+(bx&7), quarter bh=(bx>>3)&3 (tile quarters share an XCD L2).
__global__ __launch_bounds__(256, 3) void joint_mfma(const unsigned char* __restrict__ hG,
                                                     const unsigned char* __restrict__ Wf,
                                                     const float* __restrict__ bout,
                                                     const int* __restrict__ labels,
                                                     const int* __restrict__ pblank,
                                                     float* __restrict__ Spart,
                                                     float* __restrict__ blp,
                                                     float* __restrict__ llp) {
    __shared__ float ps[4][64];

    int tid  = threadIdx.x;
    int bx   = blockIdx.x;
    int tile = (bx >> 5) * 8 + (bx & 7);
    int bh   = (bx >> 3) & 3;
    int c0   = tile * 64;
    int wc = tid >> 6, lane = tid & 63;
    int lg = lane >> 4, ln = lane & 15;

    const long* hf   = (const long*)(hG + (size_t)tile * 32768) + lane;
    const long* wfbL = (const long*)Wf + (((bh << 4) + (wc << 2)) << 10) + lane;

    long bf[3][4];
    long af[3][4];
#pragma unroll
    for (int ni = 0; ni < 4; ++ni) bf[0][ni] = wfbL[ni * 1024];
#pragma unroll
    for (int ni = 0; ni < 4; ++ni) bf[1][ni] = wfbL[ni * 1024 + 64];
#pragma unroll
    for (int mi = 0; mi < 4; ++mi) af[0][mi] = hf[(mi << 10)];
#pragma unroll
    for (int mi = 0; mi < 4; ++mi) af[1][mi] = hf[(mi << 10) + 64];

    f32x4 acc[4][4] = {};
#pragma unroll
    for (int kt = 0; kt < 16; ++kt) {
        const int cur3 = kt % 3;
        const int pf3  = (kt + 2) % 3;
#pragma unroll
        for (int ni = 0; ni < 4; ++ni) {
            if (ni == 0 && kt < 14) {
#pragma unroll
                for (int mi = 0; mi < 4; ++mi)
                    af[pf3][mi] = hf[(mi << 10) + ((kt + 2) << 6)];
            }
            if (kt < 14) bf[pf3][ni] = wfbL[ni * 1024 + (kt + 2) * 64];
            __builtin_amdgcn_s_setprio(1);
#pragma unroll
            for (int mi = 0; mi < 4; ++mi)
                acc[mi][ni] = __builtin_amdgcn_mfma_f32_16x16x32_fp8_fp8(
                    af[cur3][mi], bf[cur3][ni], acc[mi][ni], 0, 0, 0);
            __builtin_amdgcn_s_setprio(0);
        }
    }

    // ---- epilogue: bias, partial exp-sum over this quarter's 256 cols, raw gather ----
    float bo[4];
#pragma unroll
    for (int ni = 0; ni < 4; ++ni) bo[ni] = bout[(bh << 8) + (wc << 6) + (ni << 4) + ln];
#pragma unroll
    for (int mi = 0; mi < 4; ++mi)
#pragma unroll
        for (int ni = 0; ni < 4; ++ni)
#pragma unroll
            for (int r = 0; r < 4; ++r) acc[mi][ni][r] += bo[ni];

#pragma unroll
    for (int mi = 0; mi < 4; ++mi) {
#pragma unroll
        for (int r = 0; r < 4; ++r) {
            float s = 0.f;
#pragma unroll
            for (int ni = 0; ni < 4; ++ni) s += __expf(acc[mi][ni][r]);
            s += __shfl_xor(s, 1);
            s += __shfl_xor(s, 2);
            s += __shfl_xor(s, 4);
            s += __shfl_xor(s, 8);
            if (ln == 0) ps[wc][mi * 16 + lg * 4 + r] = s;
        }
    }
    __syncthreads();
    if (tid < 64) {
        float S = ps[0][tid] + ps[1][tid] + ps[2][tid] + ps[3][tid];
        Spart[(size_t)bh * NCELL + c0 + tid] = S;
    }

    int blank = *pblank;
#pragma unroll
    for (int mi = 0; mi < 4; ++mi) {
#pragma unroll
        for (int r = 0; r < 4; ++r) {
            int row  = mi * 16 + lg * 4 + r;
            int cell = c0 + row;
            unsigned epRow = (unsigned)cell / 65u;
            int u = cell - (int)epRow * 65;
            int b = (int)(epRow >> 8);
            int lab = (u < U_) ? labels[(b << 6) + u] : -1;
#pragma unroll
            for (int ni = 0; ni < 4; ++ni) {
                int col = (bh << 8) + (wc << 6) + (ni << 4) + ln;
                float lgt = acc[mi][ni][r];
                if (col == blank) blp[cell] = lgt;                            // raw
                if (col == lab)   llp[(size_t)(((int)epRow << 6) + u)] = lgt; // raw
            }
        }
    }
}

// ---- Pass 2: lse = log(S0+S1+S2+S3); subtract from raw blank/label logits ----
__global__ __launch_bounds__(256) void pass2_kernel(const float* __restrict__ Spart,
                                                    float* __restrict__ blp,
                                                    float* __restrict__ llp) {
    int idx = blockIdx.x * 256 + threadIdx.x;
    if (idx >= NCELL) return;
    float lse = __logf(Spart[idx] + Spart[NCELL + idx] +
                       Spart[2 * NCELL + idx] + Spart[3 * NCELL + idx]);
    blp[idx] -= lse;
    unsigned epRow = (unsigned)idx / 65u;
    int u = idx - (int)epRow * 65;
    if (u < U_) llp[(size_t)((epRow << 6) + u)] -= lse;
}

// ------- Kernel S1: segment-operator build (R18: batch-preload + full unroll) ---------
__global__ __launch_bounds__(64) void segscan_kernel(const float* __restrict__ blp,
                                                     const float* __restrict__ llp,
                                                     const int* __restrict__ enc_lens,
                                                     float* __restrict__ Mbuf) {
    const float K2 = 1.4426950408889634f;
    int idx  = blockIdx.x;
    int v    = idx % 65;
    int seg  = (idx / 65) % NSEG;
    int b    = idx / (65 * NSEG);
    int lane = threadIdx.x;
    int el   = enc_lens[b];
    int t0   = seg * SEGLEN;
    if (t0 >= el) return;
    const float* bb = blp + (size_t)b * T_ * UP1;
    const float* lb = llp + (size_t)b * T_ * U_;

    float bvK[SEGLEN], lvK[SEGLEN], b64K[SEGLEN];
#pragma unroll
    for (int j = 0; j < SEGLEN; ++j) {
        int t  = t0 + j;
        int tc = (t < el) ? t : (el - 1);
        bvK[j]  = bb[tc * UP1 + lane] * K2;
        b64K[j] = bb[tc * UP1 + 64] * K2;
        lvK[j]  = lb[tc * U_ + lane] * K2;
    }

    float alpha   = (lane == v) ? 0.f : LOG0;
    float alpha64 = (v == 64) ? 0.f : LOG0;

#pragma unroll
    for (int j = 0; j < SEGLEN; ++j) {
        if (t0 + j < el) {
            float P = wave_prefix_sum(lvK[j]);
            float L = dpps<0x111, 0xf>(P);
            float P15 = rdlane(P, 15), P31 = rdlane(P, 31), P47 = rdlane(P, 47);
            if (lane == 0)  L = 0.f;
            if (lane == 16) L = P15;
            if (lane == 32) L = P31;
            if (lane == 48) L = P47;
            float P63 = rdlane(P, 63);
            float x   = alpha + bvK[j] - L;
            float x64 = alpha64 + b64K[j] - P63;
            float M = fmaxf(wave_max_all(x), x64);
            float S = wave_prefix_sum(__builtin_amdgcn_exp2f(x - M));
            float S63 = rdlane(S, 63);
            alpha   = L + M + __builtin_amdgcn_logf(S);
            alpha64 = P63 + M +
                      __builtin_amdgcn_logf(S63 + __builtin_amdgcn_exp2f(x64 - M));
        }
    }

    float* col = Mbuf + ((size_t)((b * NSEG + seg) * 65 + v)) * MLD;
    col[lane] = fmaxf(alpha, LOG0);
    if (lane == 0) col[64] = fmaxf(alpha64, LOG0);
}

// ------- Kernel S2: apply segment operators sequentially. 1 block/batch, 1 wave. ------
__global__ __launch_bounds__(64) void apply_kernel(const float* __restrict__ Mbuf,
                                                   const float* __restrict__ blp,
                                                   const int* __restrict__ enc_lens,
                                                   const int* __restrict__ label_lens,
                                                   float* __restrict__ lossBuf) {
    __shared__ float Ml[65 * MLD];
    __shared__ float xv[66];
    const float K2  = 1.4426950408889634f;
    const float LN2 = 0.6931471805599453f;
    int b    = blockIdx.x;
    int lane = threadIdx.x;
    int el = enc_lens[b];
    int ll = label_lens[b];

    xv[lane] = (lane == 0) ? 0.f : LOG0;
    if (lane == 0) xv[64] = LOG0;
    __syncthreads();

    for (int seg = 0; seg < NSEG; ++seg) {
        if (seg * SEGLEN >= el) break;
        const float* src = Mbuf + (size_t)((b * NSEG + seg) * 65) * MLD;
        for (int i = lane; i < 65 * MLD; i += 64) Ml[i] = src[i];
        __syncthreads();
        float m = LOG0;
#pragma unroll 5
        for (int vv = 0; vv < 65; ++vv) m = fmaxf(m, Ml[vv * MLD + lane] + xv[vv]);
        m = fmaxf(m, LOG0);
        float s = 0.f;
#pragma unroll 5
        for (int vv = 0; vv < 65; ++vv)
            s += __builtin_amdgcn_exp2f(Ml[vv * MLD + lane] + xv[vv] - m);
        float y = fmaxf(m + __builtin_amdgcn_logf(s), LOG0);
        float t64  = xv[lane] + Ml[lane * MLD + 64];
        float t64b = xv[64] + Ml[64 * MLD + 64];
        float m64 = fmaxf(fmaxf(wave_max_all(t64), t64b), LOG0);
        float s64 = rdlane(wave_prefix_sum(__builtin_amdgcn_exp2f(t64 - m64)), 63);
        s64 += __builtin_amdgcn_exp2f(t64b - m64);
        float y64 = fmaxf(m64 + __builtin_amdgcn_logf(s64), LOG0);
        __syncthreads();
        xv[lane] = y;
        if (lane == 0) xv[64] = y64;
        __syncthreads();
    }

    if (lane == 0) {
        float aU = (ll < 64) ? xv[ll] : xv[64];
        float term = blp[(size_t)b * T_ * UP1 + (el - 1) * UP1 + ll] * K2;
        lossBuf[b] = -(aU + term) * LN2;
    }
}

// ---- Finalize: mean of per-batch losses ----
__global__ __launch_bounds__(64) void finalize_kernel(const float* __restrict__ lossBuf,
                                                      float* __restrict__ out) {
    if (threadIdx.x == 0) {
        float s = 0.f;
        for (int i = 0; i < B_; ++i) s += lossBuf[i];
        out[0] = s / (float)B_;
    }
}

extern "C" void kernel_launch(void* const* d_in, const int* in_sizes, int n_in,
                              void* d_out, int out_size, void* d_ws, size_t ws_size,
                              hipStream_t stream) {
    (void)in_sizes; (void)n_in; (void)out_size; (void)ws_size;
    const float* enc        = (const float*)d_in[0];
    const float* pred       = (const float*)d_in[1];
    const float* W_enc      = (const float*)d_in[2];
    const float* W_pred     = (const float*)d_in[3];
    const float* b_joint    = (const float*)d_in[4];
    const float* W_out      = (const float*)d_in[5];
    const float* b_out      = (const float*)d_in[6];
    const int*   labels     = (const int*)d_in[7];
    const int*   enc_lens   = (const int*)d_in[8];
    const int*   label_lens = (const int*)d_in[9];
    const int*   blank_id   = (const int*)d_in[10];

    float* ep  = (float*)d_ws;                      // B*T*J   = 1,048,576 f
    float* pp  = ep  + (size_t)B_ * T_ * J_;        // B*65*J  =   266,240 f
    float* blp = pp  + (size_t)B_ * UP1 * J_;       // B*T*65  =   133,120 f
    float* llp = blp + (size_t)B_ * T_ * UP1;       // B*T*64  =   131,072 f
    unsigned char* Wf = (unsigned char*)(llp + (size_t)B_ * T_ * U_);  // 512KB frag fp8
    float* Spart = (float*)(Wf + (size_t)V_ * J_);  // 4 * NCELL f32
    unsigned char* hG = (unsigned char*)(Spart + (size_t)4 * NCELL);   // NCELL*512 fp8
    float* lossBuf = (float*)(hG + (size_t)NCELL * 512);               // B_ f32
    float* Mbuf    = lossBuf + 64;                  // B_*8*65*66 f32 = 1.1 MB

    // bf16 staging buffers alias hG (dead before hgen writes it)
    unsigned short* encB  = (unsigned short*)hG;            // 2048*640 bf16
    unsigned short* predB = encB + (size_t)2048 * DE;       // 520*640 bf16
    unsigned short* wf2e  = predB + (size_t)520 * DE;       // 640*512 bf16 frag-major
    unsigned short* wf2p  = wf2e + (size_t)DE * J_;

    prep_kernel<<<dim3(1635), dim3(256), 0, stream>>>(W_enc, W_pred, enc, pred, W_out,
                                                      wf2e, wf2p, encB, predB, Wf);
    gemm_mfma<<<dim3(41, 8), dim3(64), 0, stream>>>(encB, predB, wf2e, wf2p, b_joint,
                                                    ep, pp);
    hgen_kernel<<<dim3(NCELL / 64), dim3(512), 0, stream>>>(ep, pp, hG);
    joint_mfma<<<dim3(NCELL / 64 * 4), dim3(256), 0, stream>>>(
        hG, Wf, b_out, labels, blank_id, Spart, blp, llp);
    pass2_kernel<<<dim3((NCELL + 255) / 256), dim3(256), 0, stream>>>(Spart, blp, llp);
    segscan_kernel<<<dim3(B_ * NSEG * 65), dim3(64), 0, stream>>>(blp, llp, enc_lens,
                                                                  Mbuf);
    apply_kernel<<<dim3(B_), dim3(64), 0, stream>>>(Mbuf, blp, enc_lens, label_lens,
                                                    lossBuf);
    finalize_kernel<<<dim3(1), dim3(64), 0, stream>>>(lossBuf, (float*)d_out);
}

// Round 21
// 264.355 us; speedup vs baseline: 1.2157x; 1.2157x over previous
//
#include <hip/hip_runtime.h>
#include <math.h>

#define B_   8
#define T_   256
#define U_   64
#define UP1  65
#define DE   640
#define J_   512
#define V_   1024
#define NCELL (B_ * T_ * UP1)
#define LOG0 -1e30f
#define NSEG 8
#define SEGLEN 32
#define MLD  66   // matrix column leading dim (65 rows + 1 pad)

typedef __attribute__((ext_vector_type(4))) float f32x4;
typedef __attribute__((ext_vector_type(8))) short short8;

__device__ __forceinline__ unsigned short f2bf(float x) {
    union { float f; unsigned int u; } c; c.f = x;
    unsigned int r = (c.u + 0x7fffu + ((c.u >> 16) & 1u)) >> 16;  // RNE
    return (unsigned short)r;
}

// ---------------- DPP wave64 scan/reduce helpers -------------------------------------
template<int CTRL, int RM>
__device__ __forceinline__ float dppz(float x) {
    return __builtin_bit_cast(float,
        __builtin_amdgcn_update_dpp(0, __builtin_bit_cast(int, x), CTRL, RM, 0xf, false));
}
template<int CTRL, int RM>
__device__ __forceinline__ float dpps(float x) {
    int xi = __builtin_bit_cast(int, x);
    return __builtin_bit_cast(float,
        __builtin_amdgcn_update_dpp(xi, xi, CTRL, RM, 0xf, false));
}
__device__ __forceinline__ float wave_prefix_sum(float v) {
    v += dppz<0x111, 0xf>(v);
    v += dppz<0x112, 0xf>(v);
    v += dppz<0x114, 0xf>(v);
    v += dppz<0x118, 0xf>(v);
    v += dppz<0x142, 0xa>(v);
    v += dppz<0x143, 0xc>(v);
    return v;
}
__device__ __forceinline__ float wave_max_all(float v) {
    v = fmaxf(v, dpps<0x111, 0xf>(v));
    v = fmaxf(v, dpps<0x112, 0xf>(v));
    v = fmaxf(v, dpps<0x114, 0xf>(v));
    v = fmaxf(v, dpps<0x118, 0xf>(v));
    v = fmaxf(v, dpps<0x142, 0xa>(v));
    v = fmaxf(v, dpps<0x143, 0xc>(v));
    return __builtin_bit_cast(float,
        __builtin_amdgcn_readlane(__builtin_bit_cast(int, v), 63));
}
__device__ __forceinline__ float rdlane(float v, int l) {
    return __builtin_bit_cast(float,
        __builtin_amdgcn_readlane(__builtin_bit_cast(int, v), l));
}

// LDS swizzle for fp8 hB: row m (512B rows), cb = column byte offset (8B granular).
__device__ __forceinline__ unsigned hb8(unsigned m, unsigned cb) {
    return m * 512u + (cb ^ ((m & 15u) << 3));
}

// ---- Kernel P: prep (weights + inputs + W_out fp8). Block ranges:
// [0,160) wf2e, [160,320) wf2p, [320,960) enc->bf16, [960,1123) pred->bf16,
// [1123,1635) W_out -> fp8 frag-major Wf.
__global__ __launch_bounds__(256) void prep_kernel(const float* __restrict__ We,
                                                   const float* __restrict__ Wp,
                                                   const float* __restrict__ enc,
                                                   const float* __restrict__ pred,
                                                   const float* __restrict__ Wout,
                                                   unsigned short* __restrict__ wf2e,
                                                   unsigned short* __restrict__ wf2p,
                                                   unsigned short* __restrict__ encB,
                                                   unsigned short* __restrict__ predB,
                                                   unsigned char* __restrict__ Wf) {
    int bx = blockIdx.x, tid = threadIdx.x;
    if (bx < 320) {
        const float* W = (bx < 160) ? We : Wp;
        unsigned short* dst = (bx < 160) ? wf2e : wf2p;
        int gid = ((bx < 160) ? bx : bx - 160) * 256 + tid;
        int lane = gid & 63, ktl = gid >> 6;
        int kt = ktl % 20, tl = ktl / 20;
        int lg = lane >> 4, ln = lane & 15;
        int col = tl * 16 + ln;
        short8 v;
#pragma unroll
        for (int j = 0; j < 8; ++j)
            v[j] = (short)f2bf(W[(size_t)(kt * 32 + lg * 8 + j) * J_ + col]);
        *(short8*)(dst + (size_t)gid * 8) = v;
    } else if (bx < 960) {
        int gid = (bx - 320) * 256 + tid;
        const float* s = enc + (size_t)gid * 8;
        float4 a = *(const float4*)s, b = *(const float4*)(s + 4);
        short8 v;
        v[0] = (short)f2bf(a.x); v[1] = (short)f2bf(a.y);
        v[2] = (short)f2bf(a.z); v[3] = (short)f2bf(a.w);
        v[4] = (short)f2bf(b.x); v[5] = (short)f2bf(b.y);
        v[6] = (short)f2bf(b.z); v[7] = (short)f2bf(b.w);
        *(short8*)(encB + (size_t)gid * 8) = v;
    } else if (bx < 1123) {
        int gid = (bx - 960) * 256 + tid;
        if (gid < 41600) {
            const float* s = pred + (size_t)gid * 8;
            float4 a = *(const float4*)s, b = *(const float4*)(s + 4);
            short8 v;
            v[0] = (short)f2bf(a.x); v[1] = (short)f2bf(a.y);
            v[2] = (short)f2bf(a.z); v[3] = (short)f2bf(a.w);
            v[4] = (short)f2bf(b.x); v[5] = (short)f2bf(b.y);
            v[6] = (short)f2bf(b.z); v[7] = (short)f2bf(b.w);
            *(short8*)(predB + (size_t)gid * 8) = v;
        }
    } else {
        // W_out[512][1024] -> fp8 frag-major (round-6 K32 layout)
        __shared__ float tile[32][33];
        int bx2 = bx - 1123;                 // 0..511
        int tx = tid & 31, ty = tid >> 5;
        int v0 = (bx2 & 31) * 32, k0 = (bx2 >> 5) * 32;
#pragma unroll
        for (int i = 0; i < 4; ++i)
            tile[ty + i * 8][tx] = Wout[(size_t)(k0 + ty + i * 8) * V_ + v0 + tx];
        __syncthreads();
        if (tid < 128) {
            int vl = tid >> 2, lg = tid & 3;
            int v  = v0 + vl;
            float x[8];
#pragma unroll
            for (int j = 0; j < 8; ++j) x[j] = tile[lg * 8 + j][vl];
            int lo = 0, hi = 0;
            lo = __builtin_amdgcn_cvt_pk_fp8_f32(x[0], x[1], lo, false);
            lo = __builtin_amdgcn_cvt_pk_fp8_f32(x[2], x[3], lo, true);
            hi = __builtin_amdgcn_cvt_pk_fp8_f32(x[4], x[5], hi, false);
            hi = __builtin_amdgcn_cvt_pk_fp8_f32(x[6], x[7], hi, true);
            int tl = v >> 4, ln = v & 15, kt = k0 >> 5;
            *(int2*)(Wf + tl * 8192 + kt * 512 + (lg * 16 + ln) * 8) = make_int2(lo, hi);
        }
    }
}

// ---- Kernel A: bf16 MFMA input GEMM (enc & pred in one dispatch). 1 wave = 64x64. ----
__global__ __launch_bounds__(64) void gemm_mfma(const unsigned short* __restrict__ encB,
                                                const unsigned short* __restrict__ predB,
                                                const unsigned short* __restrict__ wf2e,
                                                const unsigned short* __restrict__ wf2p,
                                                const float* __restrict__ bj,
                                                float* __restrict__ ep,
                                                float* __restrict__ pp) {
    int rt = blockIdx.x, ct = blockIdx.y;
    int lane = threadIdx.x;
    const unsigned short* A;
    const short8* wp;
    float* C;
    const float* bias;
    int M, row0;
    if (rt < 32) { A = encB;  wp = (const short8*)wf2e; C = ep; bias = bj;      M = 2048; row0 = rt * 64; }
    else         { A = predB; wp = (const short8*)wf2p; C = pp; bias = nullptr; M = 520;  row0 = (rt - 32) * 64; }
    int lg = lane >> 4, ln = lane & 15;

    int r_[4];
#pragma unroll
    for (int mi = 0; mi < 4; ++mi) {
        int rr = row0 + mi * 16 + ln;
        r_[mi] = (rr < M) ? rr : (M - 1);
    }

#define WIDX(NI, KT) (((size_t)((ct * 4 + (NI)) * 20 + (KT))) * 64 + lane)
    short8 bf[3][4], af[2][4];
#pragma unroll
    for (int ni = 0; ni < 4; ++ni) bf[0][ni] = wp[WIDX(ni, 0)];
#pragma unroll
    for (int ni = 0; ni < 4; ++ni) bf[1][ni] = wp[WIDX(ni, 1)];
#pragma unroll
    for (int mi = 0; mi < 4; ++mi)
        af[0][mi] = *(const short8*)(A + (size_t)r_[mi] * DE + lg * 8);

    f32x4 acc[4][4] = {};
#pragma unroll
    for (int kt = 0; kt < 20; ++kt) {
        const int cur3 = kt % 3;
        const int pf3  = (kt + 2) % 3;
        const int cur  = kt & 1, nxt = cur ^ 1;
#pragma unroll
        for (int ni = 0; ni < 4; ++ni) {
            if (kt < 18) bf[pf3][ni] = wp[WIDX(ni, kt + 2)];
            __builtin_amdgcn_s_setprio(1);
#pragma unroll
            for (int mi = 0; mi < 4; ++mi)
                acc[mi][ni] = __builtin_amdgcn_mfma_f32_16x16x32_bf16(
                    af[cur][mi], bf[cur3][ni], acc[mi][ni], 0, 0, 0);
            __builtin_amdgcn_s_setprio(0);
            if (ni == 1 && kt < 19) {
#pragma unroll
                for (int mi = 0; mi < 4; ++mi)
                    af[nxt][mi] = *(const short8*)(A + (size_t)r_[mi] * DE +
                                                   (kt + 1) * 32 + lg * 8);
            }
        }
    }
#undef WIDX

#pragma unroll
    for (int mi = 0; mi < 4; ++mi) {
#pragma unroll
        for (int r = 0; r < 4; ++r) {
            int row = row0 + mi * 16 + lg * 4 + r;
            if (row >= M) continue;
#pragma unroll
            for (int ni = 0; ni < 4; ++ni) {
                int col = ct * 64 + ni * 16 + ln;
                float v = acc[mi][ni][r];
                if (bias) v += bias[col];
                C[(size_t)row * J_ + col] = v;
            }
        }
    }
}

// ---- Kernel H: h = tanh(ep+pp) fp8, pre-swizzled, OUTPUT-LINEAR (R19-validated) ------
__global__ __launch_bounds__(512) void hgen_kernel(const float* __restrict__ ep,
                                                   const float* __restrict__ pp,
                                                   unsigned char* __restrict__ hG) {
    int tid  = threadIdx.x;
    int tile = blockIdx.x;
    unsigned char* outb = hG + (size_t)tile * 32768;
#pragma unroll
    for (int i = 0; i < 4; ++i) {
        int g   = tid + i * 512;
        int row = g >> 5;
        int lin9 = (g & 31) * 16;
        unsigned swz = ((unsigned)(row & 15)) << 3;
        int k0   = lin9 ^ (int)(swz & ~8u);
        int swap = row & 1;
        int cell = tile * 64 + row;
        unsigned epRow = (unsigned)cell / 65u;
        int u = cell - (int)epRow * 65;
        int b = (int)(epRow >> 8);
        const float* epr = ep + (size_t)epRow * J_ + k0;
        const float* ppr = pp + (size_t)(b * UP1 + u) * J_ + k0;
        float t[16];
#pragma unroll
        for (int q = 0; q < 4; ++q) {
            float4 e = *(const float4*)(epr + q * 4);
            float4 p = *(const float4*)(ppr + q * 4);
            float xs[4] = {e.x + p.x, e.y + p.y, e.z + p.z, e.w + p.w};
#pragma unroll
            for (int j = 0; j < 4; ++j) {
                float e2 = __expf(2.f * xs[j]);
                t[q * 4 + j] = 1.f - 2.f / (e2 + 1.f);
            }
        }
        int a0 = 0, a1 = 0, b0 = 0, b1 = 0;
        a0 = __builtin_amdgcn_cvt_pk_fp8_f32(t[0], t[1], a0, false);
        a0 = __builtin_amdgcn_cvt_pk_fp8_f32(t[2], t[3], a0, true);
        a1 = __builtin_amdgcn_cvt_pk_fp8_f32(t[4], t[5], a1, false);
        a1 = __builtin_amdgcn_cvt_pk_fp8_f32(t[6], t[7], a1, true);
        b0 = __builtin_amdgcn_cvt_pk_fp8_f32(t[8], t[9], b0, false);
        b0 = __builtin_amdgcn_cvt_pk_fp8_f32(t[10], t[11], b0, true);
        b1 = __builtin_amdgcn_cvt_pk_fp8_f32(t[12], t[13], b1, false);
        b1 = __builtin_amdgcn_cvt_pk_fp8_f32(t[14], t[15], b1, true);
        int4 w = swap ? make_int4(b0, b1, a0, a1) : make_int4(a0, a1, b0, b1);
        *(int4*)(outb + g * 16) = w;
    }
}

// ---- Kernel B: fp8-K32 joint, reg staging, XCD-grouped, (256,3) — R19-validated -----
__global__ __launch_bounds__(256, 3) void joint_mfma(const unsigned char* __restrict__ hG,
                                                     const unsigned char* __restrict__ Wf,
                                                     const float* __restrict__ bout,
                                                     const int* __restrict__ labels,
                                                     const int* __restrict__ pblank,
                                                     float* __restrict__ Spart,
                                                     float* __restrict__ blp,
                                                     float* __restrict__ llp) {
    __shared__ __align__(16) unsigned char hB[64 * 512];
    __shared__ float ps[4][64];

    int tid  = threadIdx.x;
    int bx   = blockIdx.x;
    int tile = (bx >> 5) * 8 + (bx & 7);
    int bh   = (bx >> 3) & 3;
    int c0   = tile * 64;
    int wc = tid >> 6, lane = tid & 63;
    int lg = lane >> 4, ln = lane & 15;

    const long* wfbL = (const long*)Wf + (((bh << 4) + (wc << 2)) << 10) + lane;

    long bf[3][4];
    long af[2][4];

    // ---- stage: linear 32KB reg copy hG -> LDS, bf prologue overlapped ----
    {
        int4 v[8];
        const int4* g = (const int4*)(hG + (size_t)tile * 32768) + tid;
#pragma unroll
        for (int i = 0; i < 8; ++i) v[i] = g[i * 256];
#pragma unroll
        for (int ni = 0; ni < 4; ++ni) bf[0][ni] = wfbL[ni * 1024];
#pragma unroll
        for (int ni = 0; ni < 4; ++ni) bf[1][ni] = wfbL[ni * 1024 + 64];
#pragma unroll
        for (int i = 0; i < 8; ++i) ((int4*)hB)[tid + i * 256] = v[i];
    }
    __syncthreads();

    f32x4 acc[4][4] = {};
#pragma unroll
    for (int mi = 0; mi < 4; ++mi)
        af[0][mi] = *(const long*)(hB + hb8((unsigned)(mi * 16 + ln), (unsigned)(lg * 8)));

#pragma unroll
    for (int kt = 0; kt < 16; ++kt) {
        const int cur3 = kt % 3;
        const int pf3  = (kt + 2) % 3;
        const int cur  = kt & 1, nxt = cur ^ 1;
#pragma unroll
        for (int ni = 0; ni < 4; ++ni) {
            if (kt < 14) bf[pf3][ni] = wfbL[ni * 1024 + (kt + 2) * 64];
            __builtin_amdgcn_s_setprio(1);
#pragma unroll
            for (int mi = 0; mi < 4; ++mi)
                acc[mi][ni] = __builtin_amdgcn_mfma_f32_16x16x32_fp8_fp8(
                    af[cur][mi], bf[cur3][ni], acc[mi][ni], 0, 0, 0);
            __builtin_amdgcn_s_setprio(0);
            if (ni == 1 && kt < 15) {
#pragma unroll
                for (int mi = 0; mi < 4; ++mi) {
                    unsigned m  = (unsigned)(mi * 16 + ln);
                    unsigned cb = (unsigned)((kt + 1) * 32 + lg * 8);
                    af[nxt][mi] = *(const long*)(hB + hb8(m, cb));
                }
            }
        }
    }

    // ---- epilogue: bias, partial exp-sum over this quarter's 256 cols, raw gather ----
    float bo[4];
#pragma unroll
    for (int ni = 0; ni < 4; ++ni) bo[ni] = bout[(bh << 8) + (wc << 6) + (ni << 4) + ln];
#pragma unroll
    for (int mi = 0; mi < 4; ++mi)
#pragma unroll
        for (int ni = 0; ni < 4; ++ni)
#pragma unroll
            for (int r = 0; r < 4; ++r) acc[mi][ni][r] += bo[ni];

#pragma unroll
    for (int mi = 0; mi < 4; ++mi) {
#pragma unroll
        for (int r = 0; r < 4; ++r) {
            float s = 0.f;
#pragma unroll
            for (int ni = 0; ni < 4; ++ni) s += __expf(acc[mi][ni][r]);
            s += __shfl_xor(s, 1);
            s += __shfl_xor(s, 2);
            s += __shfl_xor(s, 4);
            s += __shfl_xor(s, 8);
            if (ln == 0) ps[wc][mi * 16 + lg * 4 + r] = s;
        }
    }
    __syncthreads();
    if (tid < 64) {
        float S = ps[0][tid] + ps[1][tid] + ps[2][tid] + ps[3][tid];
        Spart[(size_t)bh * NCELL + c0 + tid] = S;
    }

    int blank = *pblank;
#pragma unroll
    for (int mi = 0; mi < 4; ++mi) {
#pragma unroll
        for (int r = 0; r < 4; ++r) {
            int row  = mi * 16 + lg * 4 + r;
            int cell = c0 + row;
            unsigned epRow = (unsigned)cell / 65u;
            int u = cell - (int)epRow * 65;
            int b = (int)(epRow >> 8);
            int lab = (u < U_) ? labels[(b << 6) + u] : -1;
#pragma unroll
            for (int ni = 0; ni < 4; ++ni) {
                int col = (bh << 8) + (wc << 6) + (ni << 4) + ln;
                float lgt = acc[mi][ni][r];
                if (col == blank) blp[cell] = lgt;                            // raw
                if (col == lab)   llp[(size_t)(((int)epRow << 6) + u)] = lgt; // raw
            }
        }
    }
}

// ---- Pass 2: lse = log(S0+S1+S2+S3); subtract from raw blank/label logits ----
__global__ __launch_bounds__(256) void pass2_kernel(const float* __restrict__ Spart,
                                                    float* __restrict__ blp,
                                                    float* __restrict__ llp) {
    int idx = blockIdx.x * 256 + threadIdx.x;
    if (idx >= NCELL) return;
    float lse = __logf(Spart[idx] + Spart[NCELL + idx] +
                       Spart[2 * NCELL + idx] + Spart[3 * NCELL + idx]);
    blp[idx] -= lse;
    unsigned epRow = (unsigned)idx / 65u;
    int u = idx - (int)epRow * 65;
    if (u < U_) llp[(size_t)((epRow << 6) + u)] -= lse;
}

// ------- Kernel S1: segment-operator build (R18: batch-preload + full unroll) ---------
__global__ __launch_bounds__(64) void segscan_kernel(const float* __restrict__ blp,
                                                     const float* __restrict__ llp,
                                                     const int* __restrict__ enc_lens,
                                                     float* __restrict__ Mbuf) {
    const float K2 = 1.4426950408889634f;
    int idx  = blockIdx.x;
    int v    = idx % 65;
    int seg  = (idx / 65) % NSEG;
    int b    = idx / (65 * NSEG);
    int lane = threadIdx.x;
    int el   = enc_lens[b];
    int t0   = seg * SEGLEN;
    if (t0 >= el) return;
    const float* bb = blp + (size_t)b * T_ * UP1;
    const float* lb = llp + (size_t)b * T_ * U_;

    float bvK[SEGLEN], lvK[SEGLEN], b64K[SEGLEN];
#pragma unroll
    for (int j = 0; j < SEGLEN; ++j) {
        int t  = t0 + j;
        int tc = (t < el) ? t : (el - 1);
        bvK[j]  = bb[tc * UP1 + lane] * K2;
        b64K[j] = bb[tc * UP1 + 64] * K2;
        lvK[j]  = lb[tc * U_ + lane] * K2;
    }

    float alpha   = (lane == v) ? 0.f : LOG0;
    float alpha64 = (v == 64) ? 0.f : LOG0;

#pragma unroll
    for (int j = 0; j < SEGLEN; ++j) {
        if (t0 + j < el) {
            float P = wave_prefix_sum(lvK[j]);
            float L = dpps<0x111, 0xf>(P);
            float P15 = rdlane(P, 15), P31 = rdlane(P, 31), P47 = rdlane(P, 47);
            if (lane == 0)  L = 0.f;
            if (lane == 16) L = P15;
            if (lane == 32) L = P31;
            if (lane == 48) L = P47;
            float P63 = rdlane(P, 63);
            float x   = alpha + bvK[j] - L;
            float x64 = alpha64 + b64K[j] - P63;
            float M = fmaxf(wave_max_all(x), x64);
            float S = wave_prefix_sum(__builtin_amdgcn_exp2f(x - M));
            float S63 = rdlane(S, 63);
            alpha   = L + M + __builtin_amdgcn_logf(S);
            alpha64 = P63 + M +
                      __builtin_amdgcn_logf(S63 + __builtin_amdgcn_exp2f(x64 - M));
        }
    }

    float* col = Mbuf + ((size_t)((b * NSEG + seg) * 65 + v)) * MLD;
    col[lane] = fmaxf(alpha, LOG0);
    if (lane == 0) col[64] = fmaxf(alpha64, LOG0);
}

// ------- Kernel S2: apply segment operators sequentially. 1 block/batch, 1 wave. ------
__global__ __launch_bounds__(64) void apply_kernel(const float* __restrict__ Mbuf,
                                                   const float* __restrict__ blp,
                                                   const int* __restrict__ enc_lens,
                                                   const int* __restrict__ label_lens,
                                                   float* __restrict__ lossBuf) {
    __shared__ float Ml[65 * MLD];
    __shared__ float xv[66];
    const float K2  = 1.4426950408889634f;
    const float LN2 = 0.6931471805599453f;
    int b    = blockIdx.x;
    int lane = threadIdx.x;
    int el = enc_lens[b];
    int ll = label_lens[b];

    xv[lane] = (lane == 0) ? 0.f : LOG0;
    if (lane == 0) xv[64] = LOG0;
    __syncthreads();

    for (int seg = 0; seg < NSEG; ++seg) {
        if (seg * SEGLEN >= el) break;
        const float* src = Mbuf + (size_t)((b * NSEG + seg) * 65) * MLD;
        for (int i = lane; i < 65 * MLD; i += 64) Ml[i] = src[i];
        __syncthreads();
        float m = LOG0;
#pragma unroll 5
        for (int vv = 0; vv < 65; ++vv) m = fmaxf(m, Ml[vv * MLD + lane] + xv[vv]);
        m = fmaxf(m, LOG0);
        float s = 0.f;
#pragma unroll 5
        for (int vv = 0; vv < 65; ++vv)
            s += __builtin_amdgcn_exp2f(Ml[vv * MLD + lane] + xv[vv] - m);
        float y = fmaxf(m + __builtin_amdgcn_logf(s), LOG0);
        float t64  = xv[lane] + Ml[lane * MLD + 64];
        float t64b = xv[64] + Ml[64 * MLD + 64];
        float m64 = fmaxf(fmaxf(wave_max_all(t64), t64b), LOG0);
        float s64 = rdlane(wave_prefix_sum(__builtin_amdgcn_exp2f(t64 - m64)), 63);
        s64 += __builtin_amdgcn_exp2f(t64b - m64);
        float y64 = fmaxf(m64 + __builtin_amdgcn_logf(s64), LOG0);
        __syncthreads();
        xv[lane] = y;
        if (lane == 0) xv[64] = y64;
        __syncthreads();
    }

    if (lane == 0) {
        float aU = (ll < 64) ? xv[ll] : xv[64];
        float term = blp[(size_t)b * T_ * UP1 + (el - 1) * UP1 + ll] * K2;
        lossBuf[b] = -(aU + term) * LN2;
    }
}

// ---- Finalize: mean of per-batch losses ----
__global__ __launch_bounds__(64) void finalize_kernel(const float* __restrict__ lossBuf,
                                                      float* __restrict__ out) {
    if (threadIdx.x == 0) {
        float s = 0.f;
        for (int i = 0; i < B_; ++i) s += lossBuf[i];
        out[0] = s / (float)B_;
    }
}

extern "C" void kernel_launch(void* const* d_in, const int* in_sizes, int n_in,
                              void* d_out, int out_size, void* d_ws, size_t ws_size,
                              hipStream_t stream) {
    (void)in_sizes; (void)n_in; (void)out_size; (void)ws_size;
    const float* enc        = (const float*)d_in[0];
    const float* pred       = (const float*)d_in[1];
    const float* W_enc      = (const float*)d_in[2];
    const float* W_pred     = (const float*)d_in[3];
    const float* b_joint    = (const float*)d_in[4];
    const float* W_out      = (const float*)d_in[5];
    const float* b_out      = (const float*)d_in[6];
    const int*   labels     = (const int*)d_in[7];
    const int*   enc_lens   = (const int*)d_in[8];
    const int*   label_lens = (const int*)d_in[9];
    const int*   blank_id   = (const int*)d_in[10];

    float* ep  = (float*)d_ws;                      // B*T*J   = 1,048,576 f
    float* pp  = ep  + (size_t)B_ * T_ * J_;        // B*65*J  =   266,240 f
    float* blp = pp  + (size_t)B_ * UP1 * J_;       // B*T*65  =   133,120 f
    float* llp = blp + (size_t)B_ * T_ * UP1;       // B*T*64  =   131,072 f
    unsigned char* Wf = (unsigned char*)(llp + (size_t)B_ * T_ * U_);  // 512KB frag fp8
    float* Spart = (float*)(Wf + (size_t)V_ * J_);  // 4 * NCELL f32
    unsigned char* hG = (unsigned char*)(Spart + (size_t)4 * NCELL);   // NCELL*512 fp8
    float* lossBuf = (float*)(hG + (size_t)NCELL * 512);               // B_ f32
    float* Mbuf    = lossBuf + 64;                  // B_*8*65*66 f32 = 1.1 MB

    // bf16 staging buffers alias hG (dead before hgen writes it)
    unsigned short* encB  = (unsigned short*)hG;            // 2048*640 bf16
    unsigned short* predB = encB + (size_t)2048 * DE;       // 520*640 bf16
    unsigned short* wf2e  = predB + (size_t)520 * DE;       // 640*512 bf16 frag-major
    unsigned short* wf2p  = wf2e + (size_t)DE * J_;

    prep_kernel<<<dim3(1635), dim3(256), 0, stream>>>(W_enc, W_pred, enc, pred, W_out,
                                                      wf2e, wf2p, encB, predB, Wf);
    gemm_mfma<<<dim3(41, 8), dim3(64), 0, stream>>>(encB, predB, wf2e, wf2p, b_joint,
                                                    ep, pp);
    hgen_kernel<<<dim3(NCELL / 64), dim3(512), 0, stream>>>(ep, pp, hG);
    joint_mfma<<<dim3(NCELL / 64 * 4), dim3(256), 0, stream>>>(
        hG, Wf, b_out, labels, blank_id, Spart, blp, llp);
    pass2_kernel<<<dim3((NCELL + 255) / 256), dim3(256), 0, stream>>>(Spart, blp, llp);
    segscan_kernel<<<dim3(B_ * NSEG * 65), dim3(64), 0, stream>>>(blp, llp, enc_lens,
                                                                  Mbuf);
    apply_kernel<<<dim3(B_), dim3(64), 0, stream>>>(Mbuf, blp, enc_lens, label_lens,
                                                    lossBuf);
    finalize_kernel<<<dim3(1), dim3(64), 0, stream>>>(lossBuf, (float*)d_out);
}